// Round 1
// baseline (103.997 us; speedup 1.0000x reference)
//
#include <hip/hip_runtime.h>

// ---------------------------------------------------------------------------
// Compile-time Clebsch-Gordan / real Wigner-3j machinery (mirrors reference).
// ---------------------------------------------------------------------------
namespace cg {

constexpr double fact(int n) {
  double r = 1.0;
  for (int i = 2; i <= n; ++i) r *= (double)i;
  return r;
}

constexpr double csqrt(double x) {
  if (x <= 0.0) return 0.0;
  double g = x < 1.0 ? 1.0 : x;
  for (int i = 0; i < 80; ++i) g = 0.5 * (g + x / g);
  return g;
}

struct cplx { double re, im; };
constexpr cplx cmul(cplx a, cplx b) {
  return cplx{a.re * b.re - a.im * b.im, a.re * b.im + a.im * b.re};
}

// Racah formula, e3nn convention: <j1 m1 j2 m2 | j3 m3>
constexpr double su2_cg(int j1, int m1, int j2, int m2, int j3, int m3) {
  if (m3 != m1 + m2) return 0.0;
  int vmin = -j1 + j2 + m3;
  if (-j1 + m1 > vmin) vmin = -j1 + m1;
  if (0 > vmin) vmin = 0;
  int vmax = j2 + j3 + m1;
  if (j3 - j1 + j2 < vmax) vmax = j3 - j1 + j2;
  if (j3 + m3 < vmax) vmax = j3 + m3;
  const double C = csqrt((2.0 * j3 + 1.0)
      * fact(j3 + j1 - j2) * fact(j3 - j1 + j2) * fact(j1 + j2 - j3)
      * fact(j3 + m3) * fact(j3 - m3)
      / (fact(j1 + j2 + j3 + 1) * fact(j1 - m1) * fact(j1 + m1)
         * fact(j2 - m2) * fact(j2 + m2)));
  double S = 0.0;
  for (int v = vmin; v <= vmax; ++v) {
    const double sgn = ((v + j2 + m2) & 1) ? -1.0 : 1.0;
    S += sgn * (fact(j2 + j3 + m1 - v) * fact(j1 - m1 + v)
         / (fact(v) * fact(j3 - j1 + j2 - v) * fact(j3 + m3 - v)
            * fact(v + j1 - j2 - m3)));
  }
  return C * S;
}

template <int L> struct QMat { cplx q[2 * L + 1][2 * L + 1]; };

// real -> complex SH change of basis (e3nn convention), rows m', cols m
template <int L>
constexpr QMat<L> make_q() {
  QMat<L> Q{};
  const double s = 1.0 / csqrt(2.0);
  for (int m = -L; m < 0; ++m) {
    Q.q[L + m][L - m] = cplx{s, 0.0};     // col l+|m|
    Q.q[L + m][L + m] = cplx{0.0, -s};    // col l-|m|
  }
  Q.q[L][L] = cplx{1.0, 0.0};
  for (int m = 1; m <= L; ++m) {
    const double sg = (m & 1) ? -1.0 : 1.0;
    Q.q[L + m][L + m] = cplx{sg * s, 0.0};
    Q.q[L + m][L - m] = cplx{0.0, sg * s};
  }
  cplx p{1.0, 0.0};                        // (-i)^L prefactor
  for (int t = 0; t < L; ++t) p = cmul(p, cplx{0.0, -1.0});
  for (int r = 0; r < 2 * L + 1; ++r)
    for (int c = 0; c < 2 * L + 1; ++c)
      Q.q[r][c] = cmul(p, Q.q[r][c]);
  return Q;
}

template <int L, int L1, int L2>
struct W3 { float t[2 * L + 1][2 * L1 + 1][2 * L2 + 1]; };

// real-basis wigner3j(L, L1, L2) * sqrt(2L+1), exactly as the reference CG dict
template <int L, int L1, int L2>
constexpr W3<L, L1, L2> wigner() {
  const QMat<L>  Q1 = make_q<L>();
  const QMat<L1> Q2 = make_q<L1>();
  const QMat<L2> Q3 = make_q<L2>();
  // SU(2) CG tensor, axes (m over L, m1 over L1, m2 over L2), / sqrt(2*L2+1)
  double C[2 * L + 1][2 * L1 + 1][2 * L2 + 1] = {};
  for (int m1 = -L; m1 <= L; ++m1)
    for (int m2 = -L1; m2 <= L1; ++m2) {
      const int m3 = m1 + m2;
      if (m3 >= -L2 && m3 <= L2)
        C[L + m1][L1 + m2][L2 + m3] = su2_cg(L, m1, L1, m2, L2, m3);
    }
  const double scale = csqrt(2.0 * L + 1.0) / csqrt(2.0 * L2 + 1.0);
  W3<L, L1, L2> R{};
  for (int j = 0; j < 2 * L + 1; ++j)
    for (int l = 0; l < 2 * L1 + 1; ++l)
      for (int m = 0; m < 2 * L2 + 1; ++m) {
        cplx acc{0.0, 0.0};
        for (int i = 0; i < 2 * L + 1; ++i) {
          const cplx q1 = Q1.q[i][j];
          if (q1.re == 0.0 && q1.im == 0.0) continue;
          for (int k = 0; k < 2 * L1 + 1; ++k) {
            const cplx q2 = Q2.q[k][l];
            if (q2.re == 0.0 && q2.im == 0.0) continue;
            const cplx q12 = cmul(q1, q2);
            for (int n = 0; n < 2 * L2 + 1; ++n) {
              const double c = C[i][k][n];
              if (c == 0.0) continue;
              const cplx q3c{Q3.q[n][m].re, -Q3.q[n][m].im};  // conj
              const cplx term = cmul(q12, q3c);
              acc.re += term.re * c;
              acc.im += term.im * c;
            }
          }
        }
        R.t[j][l][m] = (float)(acc.re * scale);
      }
  return R;
}

// the 8 tensors needed (each its own top-level constexpr evaluation)
constexpr W3<0, 1, 1> W011 = wigner<0, 1, 1>();
constexpr W3<1, 1, 1> W111 = wigner<1, 1, 1>();
constexpr W3<2, 1, 1> W211 = wigner<2, 1, 1>();
constexpr W3<0, 2, 2> W022 = wigner<0, 2, 2>();
constexpr W3<1, 2, 2> W122 = wigner<1, 2, 2>();
constexpr W3<2, 2, 2> W222 = wigner<2, 2, 2>();
constexpr W3<3, 2, 2> W322 = wigner<3, 2, 2>();
constexpr W3<4, 2, 2> W422 = wigner<4, 2, 2>();

}  // namespace cg

// ---------------------------------------------------------------------------
// Kernel
// ---------------------------------------------------------------------------

// out[i] = sum_{j,k} C[i][j][k] * p[j][k]; C folds to literals, zeros DCE'd.
template <int L, int L1, int L2>
__device__ __forceinline__ void contract(const cg::W3<L, L1, L2>& W,
                                         const float (&p)[2 * L1 + 1][2 * L2 + 1],
                                         float (&o)[2 * L + 1]) {
#pragma unroll
  for (int i = 0; i < 2 * L + 1; ++i) {
    float acc = 0.0f;
#pragma unroll
    for (int j = 0; j < 2 * L1 + 1; ++j)
#pragma unroll
      for (int k = 0; k < 2 * L2 + 1; ++k) {
        const float c = W.t[i][j][k];
        if (c != 0.0f) acc = __builtin_fmaf(c, p[j][k], acc);
      }
    o[i] = acc;
  }
}

// per-batch layouts (floats):
//  f1: [0,256) l=0 | [256,1024) l=1 (mul*3) | [1024,2304) l=2 (mul*5)
//  f2: [0,768) l=1 | [768,1536) l=1        | [1536,2816) l=2
//  out: [0,768) p0 | 768 p1l0 | 1024 p1l1 | 1792 p1l2
//       | 3072 p2l0 | 3328 p2l1 | 4096 p2l2 | 5376 p2l3 | 7168 p2l4 | 9472
__global__ __launch_bounds__(256) void tp_kernel(
    const float* __restrict__ f1, const float* __restrict__ f2,
    float* __restrict__ out, int B) {
  const int b = blockIdx.x;
  if (b >= B) return;
  const int m = threadIdx.x;  // channel 0..255
  const float* F1 = f1 + (size_t)b * 2304;
  const float* F2 = f2 + (size_t)b * 2816;
  float* O = out + (size_t)b * 9472;

  // ---- pair 0: (256,0) x (256,1): scalar * vector
  {
    const float s = F1[m];
#pragma unroll
    for (int k = 0; k < 3; ++k) O[m * 3 + k] = s * F2[m * 3 + k];
  }

  // ---- pair 1: (256,1) x (256,1) -> l = 0,1,2
  {
    float a[3], c[3];
#pragma unroll
    for (int j = 0; j < 3; ++j) a[j] = F1[256 + m * 3 + j];
#pragma unroll
    for (int k = 0; k < 3; ++k) c[k] = F2[768 + m * 3 + k];
    float p[3][3];
#pragma unroll
    for (int j = 0; j < 3; ++j)
#pragma unroll
      for (int k = 0; k < 3; ++k) p[j][k] = a[j] * c[k];
    float o0[1], o1[3], o2[5];
    contract<0, 1, 1>(cg::W011, p, o0);
    contract<1, 1, 1>(cg::W111, p, o1);
    contract<2, 1, 1>(cg::W211, p, o2);
    O[768 + m] = o0[0];
#pragma unroll
    for (int i = 0; i < 3; ++i) O[1024 + m * 3 + i] = o1[i];
#pragma unroll
    for (int i = 0; i < 5; ++i) O[1792 + m * 5 + i] = o2[i];
  }

  // ---- pair 2: (256,2) x (256,2) -> l = 0,1,2,3,4
  {
    float a[5], c[5];
#pragma unroll
    for (int j = 0; j < 5; ++j) a[j] = F1[1024 + m * 5 + j];
#pragma unroll
    for (int k = 0; k < 5; ++k) c[k] = F2[1536 + m * 5 + k];
    float p[5][5];
#pragma unroll
    for (int j = 0; j < 5; ++j)
#pragma unroll
      for (int k = 0; k < 5; ++k) p[j][k] = a[j] * c[k];
    float q0[1], q1[3], q2[5], q3[7], q4[9];
    contract<0, 2, 2>(cg::W022, p, q0);
    contract<1, 2, 2>(cg::W122, p, q1);
    contract<2, 2, 2>(cg::W222, p, q2);
    contract<3, 2, 2>(cg::W322, p, q3);
    contract<4, 2, 2>(cg::W422, p, q4);
    O[3072 + m] = q0[0];
#pragma unroll
    for (int i = 0; i < 3; ++i) O[3328 + m * 3 + i] = q1[i];
#pragma unroll
    for (int i = 0; i < 5; ++i) O[4096 + m * 5 + i] = q2[i];
#pragma unroll
    for (int i = 0; i < 7; ++i) O[5376 + m * 7 + i] = q3[i];
#pragma unroll
    for (int i = 0; i < 9; ++i) O[7168 + m * 9 + i] = q4[i];
  }
}

extern "C" void kernel_launch(void* const* d_in, const int* in_sizes, int n_in,
                              void* d_out, int out_size, void* d_ws, size_t ws_size,
                              hipStream_t stream) {
  const float* f1 = (const float*)d_in[0];
  const float* f2 = (const float*)d_in[1];
  float* out = (float*)d_out;
  const int B = in_sizes[0] / 2304;  // 8192
  tp_kernel<<<B, 256, 0, stream>>>(f1, f2, out, B);
}

// Round 3
// 94.671 us; speedup vs baseline: 1.0985x; 1.0985x over previous
//
#include <hip/hip_runtime.h>

// ---------------------------------------------------------------------------
// Compile-time Clebsch-Gordan / real Wigner-3j machinery (mirrors reference).
// ---------------------------------------------------------------------------
namespace cg {

constexpr double fact(int n) {
  double r = 1.0;
  for (int i = 2; i <= n; ++i) r *= (double)i;
  return r;
}

constexpr double csqrt(double x) {
  if (x <= 0.0) return 0.0;
  double g = x < 1.0 ? 1.0 : x;
  for (int i = 0; i < 80; ++i) g = 0.5 * (g + x / g);
  return g;
}

struct cplx { double re, im; };
constexpr cplx cmul(cplx a, cplx b) {
  return cplx{a.re * b.re - a.im * b.im, a.re * b.im + a.im * b.re};
}

// Racah formula, e3nn convention: <j1 m1 j2 m2 | j3 m3>
constexpr double su2_cg(int j1, int m1, int j2, int m2, int j3, int m3) {
  if (m3 != m1 + m2) return 0.0;
  int vmin = -j1 + j2 + m3;
  if (-j1 + m1 > vmin) vmin = -j1 + m1;
  if (0 > vmin) vmin = 0;
  int vmax = j2 + j3 + m1;
  if (j3 - j1 + j2 < vmax) vmax = j3 - j1 + j2;
  if (j3 + m3 < vmax) vmax = j3 + m3;
  const double C = csqrt((2.0 * j3 + 1.0)
      * fact(j3 + j1 - j2) * fact(j3 - j1 + j2) * fact(j1 + j2 - j3)
      * fact(j3 + m3) * fact(j3 - m3)
      / (fact(j1 + j2 + j3 + 1) * fact(j1 - m1) * fact(j1 + m1)
         * fact(j2 - m2) * fact(j2 + m2)));
  double S = 0.0;
  for (int v = vmin; v <= vmax; ++v) {
    const double sgn = ((v + j2 + m2) & 1) ? -1.0 : 1.0;
    S += sgn * (fact(j2 + j3 + m1 - v) * fact(j1 - m1 + v)
         / (fact(v) * fact(j3 - j1 + j2 - v) * fact(j3 + m3 - v)
            * fact(v + j1 - j2 - m3)));
  }
  return C * S;
}

template <int L> struct QMat { cplx q[2 * L + 1][2 * L + 1]; };

// real -> complex SH change of basis (e3nn convention), rows m', cols m
template <int L>
constexpr QMat<L> make_q() {
  QMat<L> Q{};
  const double s = 1.0 / csqrt(2.0);
  for (int m = -L; m < 0; ++m) {
    Q.q[L + m][L - m] = cplx{s, 0.0};
    Q.q[L + m][L + m] = cplx{0.0, -s};
  }
  Q.q[L][L] = cplx{1.0, 0.0};
  for (int m = 1; m <= L; ++m) {
    const double sg = (m & 1) ? -1.0 : 1.0;
    Q.q[L + m][L + m] = cplx{sg * s, 0.0};
    Q.q[L + m][L - m] = cplx{0.0, sg * s};
  }
  cplx p{1.0, 0.0};                        // (-i)^L prefactor
  for (int t = 0; t < L; ++t) p = cmul(p, cplx{0.0, -1.0});
  for (int r = 0; r < 2 * L + 1; ++r)
    for (int c = 0; c < 2 * L + 1; ++c)
      Q.q[r][c] = cmul(p, Q.q[r][c]);
  return Q;
}

template <int L, int L1, int L2>
struct W3 { float t[2 * L + 1][2 * L1 + 1][2 * L2 + 1]; };

// real-basis wigner3j(L, L1, L2) * sqrt(2L+1), exactly as the reference CG dict
template <int L, int L1, int L2>
constexpr W3<L, L1, L2> wigner() {
  const QMat<L>  Q1 = make_q<L>();
  const QMat<L1> Q2 = make_q<L1>();
  const QMat<L2> Q3 = make_q<L2>();
  double C[2 * L + 1][2 * L1 + 1][2 * L2 + 1] = {};
  for (int m1 = -L; m1 <= L; ++m1)
    for (int m2 = -L1; m2 <= L1; ++m2) {
      const int m3 = m1 + m2;
      if (m3 >= -L2 && m3 <= L2)
        C[L + m1][L1 + m2][L2 + m3] = su2_cg(L, m1, L1, m2, L2, m3);
    }
  const double scale = csqrt(2.0 * L + 1.0) / csqrt(2.0 * L2 + 1.0);
  W3<L, L1, L2> R{};
  for (int j = 0; j < 2 * L + 1; ++j)
    for (int l = 0; l < 2 * L1 + 1; ++l)
      for (int m = 0; m < 2 * L2 + 1; ++m) {
        cplx acc{0.0, 0.0};
        for (int i = 0; i < 2 * L + 1; ++i) {
          const cplx q1 = Q1.q[i][j];
          if (q1.re == 0.0 && q1.im == 0.0) continue;
          for (int k = 0; k < 2 * L1 + 1; ++k) {
            const cplx q2 = Q2.q[k][l];
            if (q2.re == 0.0 && q2.im == 0.0) continue;
            const cplx q12 = cmul(q1, q2);
            for (int n = 0; n < 2 * L2 + 1; ++n) {
              const double c = C[i][k][n];
              if (c == 0.0) continue;
              const cplx q3c{Q3.q[n][m].re, -Q3.q[n][m].im};  // conj
              const cplx term = cmul(q12, q3c);
              acc.re += term.re * c;
              acc.im += term.im * c;
            }
          }
        }
        R.t[j][l][m] = (float)(acc.re * scale);
      }
  return R;
}

constexpr W3<0, 1, 1> W011 = wigner<0, 1, 1>();
constexpr W3<1, 1, 1> W111 = wigner<1, 1, 1>();
constexpr W3<2, 1, 1> W211 = wigner<2, 1, 1>();
constexpr W3<0, 2, 2> W022 = wigner<0, 2, 2>();
constexpr W3<1, 2, 2> W122 = wigner<1, 2, 2>();
constexpr W3<2, 2, 2> W222 = wigner<2, 2, 2>();
constexpr W3<3, 2, 2> W322 = wigner<3, 2, 2>();
constexpr W3<4, 2, 2> W422 = wigner<4, 2, 2>();

}  // namespace cg

// ---------------------------------------------------------------------------
// Kernel
// ---------------------------------------------------------------------------

template <int L, int L1, int L2>
__device__ __forceinline__ void contract(const cg::W3<L, L1, L2>& W,
                                         const float (&p)[2 * L1 + 1][2 * L2 + 1],
                                         float* __restrict__ o) {
#pragma unroll
  for (int i = 0; i < 2 * L + 1; ++i) {
    float acc = 0.0f;
#pragma unroll
    for (int j = 0; j < 2 * L1 + 1; ++j)
#pragma unroll
      for (int k = 0; k < 2 * L2 + 1; ++k) {
        const float c = W.t[i][j][k];
        if (c != 0.0f) acc = __builtin_fmaf(c, p[j][k], acc);
      }
    o[i] = acc;
  }
}

// per-batch layouts (floats):
//  f1: [0,256) l=0 | [256,1024) l=1 | [1024,2304) l=2           (2304)
//  f2: [0,768) l=1 | [768,1536) l=1 | [1536,2816) l=2           (2816)
//  out: 0 p0 | 768 p1l0 | 1024 p1l1 | 1792 p1l2
//       | 3072 p2l0 | 3328 p2l1 | 4096 p2l2 | 5376 p2l3 | 7168 p2l4 | 9472
//
// One block per batch row. LDS is reused: input layout (5120 f) -> barrier ->
// output layout (9472 f). All LDS compute strides are odd => <=2-way bank
// aliasing (free on CDNA4). Global traffic is 100% float4-coalesced.
__global__ __launch_bounds__(256) void tp_kernel(
    const float* __restrict__ f1, const float* __restrict__ f2,
    float* __restrict__ out, int B) {
  __shared__ __align__(16) float lds[9472];  // 37888 B -> 4 blocks/CU
  const int b = blockIdx.x;
  if (b >= B) return;
  const int t = threadIdx.x;  // 0..255 (also the channel index in phase 2)

  // ---------------- phase 1: coalesced float4 stage-in ----------------
  // f1 = 576 float4 -> lds f4 [0,576); f2 = 704 float4 -> lds f4 [576,1280)
  {
    const float4* s1 = reinterpret_cast<const float4*>(f1 + (size_t)b * 2304);
    const float4* s2 = reinterpret_cast<const float4*>(f2 + (size_t)b * 2816);
    float4* l4 = reinterpret_cast<float4*>(lds);
#pragma unroll
    for (int k = 0; k < 2; ++k) l4[t + k * 256] = s1[t + k * 256];        // 0..511
    if (t < 64) l4[512 + t] = s1[512 + t];                                 // 512..575
#pragma unroll
    for (int k = 0; k < 2; ++k) l4[576 + t + k * 256] = s2[t + k * 256];   // 576..1087
    if (t < 192) l4[1088 + t] = s2[512 + t];                               // 1088..1279
  }
  __syncthreads();

  // ---------------- phase 2: per-channel compute (37 output regs) ------
  const int m = t;
  float r0[3];                       // pair 0
  float o0, o1[3], o2[5];            // pair 1
  float q0, q1[3], q2[5], q3[7], q4[9];  // pair 2
  {
    const float s = lds[m];
#pragma unroll
    for (int k = 0; k < 3; ++k) r0[k] = s * lds[2304 + m * 3 + k];
  }
  {
    float a[3], c[3];
#pragma unroll
    for (int j = 0; j < 3; ++j) a[j] = lds[256 + m * 3 + j];
#pragma unroll
    for (int k = 0; k < 3; ++k) c[k] = lds[2304 + 768 + m * 3 + k];
    float p[3][3];
#pragma unroll
    for (int j = 0; j < 3; ++j)
#pragma unroll
      for (int k = 0; k < 3; ++k) p[j][k] = a[j] * c[k];
    contract<0, 1, 1>(cg::W011, p, &o0);
    contract<1, 1, 1>(cg::W111, p, o1);
    contract<2, 1, 1>(cg::W211, p, o2);
  }
  {
    float a[5], c[5];
#pragma unroll
    for (int j = 0; j < 5; ++j) a[j] = lds[1024 + m * 5 + j];
#pragma unroll
    for (int k = 0; k < 5; ++k) c[k] = lds[2304 + 1536 + m * 5 + k];
    float p[5][5];
#pragma unroll
    for (int j = 0; j < 5; ++j)
#pragma unroll
      for (int k = 0; k < 5; ++k) p[j][k] = a[j] * c[k];
    contract<0, 2, 2>(cg::W022, p, &q0);
    contract<1, 2, 2>(cg::W122, p, q1);
    contract<2, 2, 2>(cg::W222, p, q2);
    contract<3, 2, 2>(cg::W322, p, q3);
    contract<4, 2, 2>(cg::W422, p, q4);
  }
  __syncthreads();  // everyone done reading input layout

  // ---------------- phase 3: scatter outputs into LDS (output layout) --
#pragma unroll
  for (int k = 0; k < 3; ++k) lds[m * 3 + k] = r0[k];
  lds[768 + m] = o0;
#pragma unroll
  for (int i = 0; i < 3; ++i) lds[1024 + m * 3 + i] = o1[i];
#pragma unroll
  for (int i = 0; i < 5; ++i) lds[1792 + m * 5 + i] = o2[i];
  lds[3072 + m] = q0;
#pragma unroll
  for (int i = 0; i < 3; ++i) lds[3328 + m * 3 + i] = q1[i];
#pragma unroll
  for (int i = 0; i < 5; ++i) lds[4096 + m * 5 + i] = q2[i];
#pragma unroll
  for (int i = 0; i < 7; ++i) lds[5376 + m * 7 + i] = q3[i];
#pragma unroll
  for (int i = 0; i < 9; ++i) lds[7168 + m * 9 + i] = q4[i];
  __syncthreads();

  // ---------------- phase 4: coalesced float4 stage-out ----------------
  {
    const float4* l4 = reinterpret_cast<const float4*>(lds);
    float4* dst = reinterpret_cast<float4*>(out + (size_t)b * 9472);
#pragma unroll
    for (int k = 0; k < 9; ++k) dst[t + k * 256] = l4[t + k * 256];  // 2304
    if (t < 64) dst[2304 + t] = l4[2304 + t];                         // 2368
  }
}

extern "C" void kernel_launch(void* const* d_in, const int* in_sizes, int n_in,
                              void* d_out, int out_size, void* d_ws, size_t ws_size,
                              hipStream_t stream) {
  const float* f1 = (const float*)d_in[0];
  const float* f2 = (const float*)d_in[1];
  float* out = (float*)d_out;
  const int B = in_sizes[0] / 2304;  // 8192
  tp_kernel<<<B, 256, 0, stream>>>(f1, f2, out, B);
}